// Round 1
// baseline (3042.766 us; speedup 1.0000x reference)
//
#include <hip/hip_runtime.h>

// MultiLayerGCN on MI355X.
// Math: h1 = relu((Anorm@x) @ W1 + b1)        [aggregate 128 feats, then GEMM]
//       t2 = h1 @ W2;  h2 = relu(Anorm@t2 + b2)
//       h3 = relu(h2 @ W3 + b3); out = relu(h3 @ W4 + b4)
// Anorm@y = scatter(dinv[src]*w*dinv[dst] * y[src] -> dst) + y * dinv^2
// GEMMs in bf16 MFMA (fp32 accum); aggregation in fp32 atomics.

typedef short bf16x8 __attribute__((ext_vector_type(8)));
typedef float f32x4 __attribute__((ext_vector_type(4)));

__device__ __forceinline__ unsigned short f2b(float f) {
    unsigned u = __builtin_bit_cast(unsigned, f);
    unsigned r = (u + 0x7FFFu + ((u >> 16) & 1u)) >> 16;
    return (unsigned short)r;
}

__global__ void k_fill1(float* p, int n) {
    int i = blockIdx.x * 256 + threadIdx.x;
    if (i < n) p[i] = 1.0f;
}

__global__ void k_degacc(const int* __restrict__ dst, const float* __restrict__ w,
                         float* __restrict__ deg, int E) {
    int i = blockIdx.x * 256 + threadIdx.x;
    if (i < E) atomicAdd(&deg[dst[i]], w[i]);
}

__global__ void k_rsqrt(float* p, int n) {
    int i = blockIdx.x * 256 + threadIdx.x;
    if (i < n) p[i] = rsqrtf(p[i]);
}

__global__ void k_norm(const int* __restrict__ src, const int* __restrict__ dst,
                       const float* __restrict__ w, const float* __restrict__ dinv,
                       float* __restrict__ nrm, int E) {
    int i = blockIdx.x * 256 + threadIdx.x;
    if (i < E) nrm[i] = dinv[src[i]] * w[i] * dinv[dst[i]];
}

// agg[i,:] = X[i,:] * dinv[i]^2   (self-loop term), F=128, one float4 per thread
__global__ void k_agg_init(const float* __restrict__ X, const float* __restrict__ dinv,
                           float* __restrict__ agg, int n4) {
    int i = blockIdx.x * 256 + threadIdx.x;
    if (i >= n4) return;
    int node = i >> 5;                 // 32 float4 per node (128 floats)
    float di = dinv[node]; di *= di;
    float4 v = ((const float4*)X)[i];
    float4 o; o.x = v.x * di; o.y = v.y * di; o.z = v.z * di; o.w = v.w * di;
    ((float4*)agg)[i] = o;
}

// 32 threads per edge, float4 each: agg[dst] += nrm[e] * X[src]
__global__ void k_scatter(const float* __restrict__ X, const int* __restrict__ src,
                          const int* __restrict__ dst, const float* __restrict__ nrm,
                          float* __restrict__ agg, int E) {
    int i = blockIdx.x * 256 + threadIdx.x;
    int e = i >> 5;
    if (e >= E) return;
    int q = i & 31;
    float s = nrm[e];
    float4 v = ((const float4*)(X + (size_t)src[e] * 128))[q];
    float* p = agg + (size_t)dst[e] * 128 + q * 4;
    atomicAdd(p + 0, s * v.x);
    atomicAdd(p + 1, s * v.y);
    atomicAdd(p + 2, s * v.z);
    atomicAdd(p + 3, s * v.w);
}

__global__ void k_f2b(const float* __restrict__ in, unsigned short* __restrict__ out, int n) {
    int i = blockIdx.x * 256 + threadIdx.x;
    if (i < n) out[i] = f2b(in[i]);
}

// out = bf16(relu(in + bias[col])), row width 128
__global__ void k_bias_relu_f2b(const float* __restrict__ in, const float* __restrict__ bias,
                                unsigned short* __restrict__ out, int n) {
    int i = blockIdx.x * 256 + threadIdx.x;
    if (i < n) {
        float v = in[i] + bias[i & 127];
        out[i] = f2b(fmaxf(v, 0.0f));
    }
}

// W [K,N] fp32 -> Wt [N,K] bf16
__global__ void k_transpose_f2b(const float* __restrict__ W, unsigned short* __restrict__ Wt,
                                int K, int N) {
    int i = blockIdx.x * 256 + threadIdx.x;
    if (i >= K * N) return;
    int k = i / N, n = i % N;
    Wt[(size_t)n * K + k] = f2b(W[i]);
}

// C[M,N] = A[M,K] @ Bt[N,K]^T  (both bf16, row-major), fp32 accumulate.
// Wave tile 64x64 (4x4 MFMA 16x16x32), block = WR x WC waves.
template <int WR, int WC, bool HAS_BIAS, bool RELU, bool OUT_BF16>
__global__ __launch_bounds__(WR * WC * 64) void gemm_bt(
    const unsigned short* __restrict__ A, const unsigned short* __restrict__ Bt,
    const float* __restrict__ bias, void* __restrict__ C, int M, int N, int K) {
    constexpr int BM = WR * 64, BN = WC * 64, NT = WR * WC * 64;
    __shared__ __align__(16) unsigned short As[BM * 32];
    __shared__ __align__(16) unsigned short Bs[BN * 32];
    const int tid = threadIdx.x;
    const int wave = tid >> 6, lane = tid & 63;
    const int wr = wave / WC, wc = wave % WC;
    const int lm = lane & 15, quad = lane >> 4;
    const int bm0 = blockIdx.y * BM, bn0 = blockIdx.x * BN;

    f32x4 acc[4][4] = {};

    const int nkb = K >> 5;
    for (int kb = 0; kb < nkb; ++kb) {
        // stage A tile [BM][32] (M-guarded) and Bt tile [BN][32]
        #pragma unroll
        for (int c = tid; c < BM * 4; c += NT) {
            int r = c >> 2, cc = c & 3;
            int gm = bm0 + r;
            int4 v = make_int4(0, 0, 0, 0);
            if (gm < M) v = *(const int4*)(A + (size_t)gm * K + kb * 32 + cc * 8);
            *(int4*)&As[r * 32 + cc * 8] = v;
        }
        #pragma unroll
        for (int c = tid; c < BN * 4; c += NT) {
            int r = c >> 2, cc = c & 3;
            int gn = bn0 + r;
            *(int4*)&Bs[r * 32 + cc * 8] =
                *(const int4*)(Bt + (size_t)gn * K + kb * 32 + cc * 8);
        }
        __syncthreads();
        bf16x8 af[4], bfr[4];
        #pragma unroll
        for (int i = 0; i < 4; i++)
            af[i] = *(const bf16x8*)&As[(wr * 64 + i * 16 + lm) * 32 + quad * 8];
        #pragma unroll
        for (int j = 0; j < 4; j++)
            bfr[j] = *(const bf16x8*)&Bs[(wc * 64 + j * 16 + lm) * 32 + quad * 8];
        #pragma unroll
        for (int i = 0; i < 4; i++)
            #pragma unroll
            for (int j = 0; j < 4; j++)
                acc[i][j] = __builtin_amdgcn_mfma_f32_16x16x32_bf16(af[i], bfr[j], acc[i][j], 0, 0, 0);
        __syncthreads();
    }

    // epilogue: C/D layout col=lane&15, row=quad*4+reg
    #pragma unroll
    for (int i = 0; i < 4; i++) {
        int mbase = bm0 + wr * 64 + i * 16 + quad * 4;
        #pragma unroll
        for (int j = 0; j < 4; j++) {
            int col = bn0 + wc * 64 + j * 16 + lm;
            float bv = HAS_BIAS ? bias[col] : 0.0f;
            f32x4 v = acc[i][j];
            #pragma unroll
            for (int r = 0; r < 4; r++) {
                int m = mbase + r;
                if (m < M) {
                    float o = v[r] + bv;
                    if (RELU) o = fmaxf(o, 0.0f);
                    if (OUT_BF16)
                        ((unsigned short*)C)[(size_t)m * N + col] = f2b(o);
                    else
                        ((float*)C)[(size_t)m * N + col] = o;
                }
            }
        }
    }
}

static inline int cdiv(long a, long b) { return (int)((a + b - 1) / b); }

extern "C" void kernel_launch(void* const* d_in, const int* in_sizes, int n_in,
                              void* d_out, int out_size, void* d_ws, size_t ws_size,
                              hipStream_t stream) {
    const float* x  = (const float*)d_in[0];
    const int*   ei = (const int*)d_in[1];
    const float* ew = (const float*)d_in[2];
    const float* W1 = (const float*)d_in[3];
    const float* b1 = (const float*)d_in[4];
    const float* W2 = (const float*)d_in[5];
    const float* b2 = (const float*)d_in[6];
    const float* W3 = (const float*)d_in[7];
    const float* b3 = (const float*)d_in[8];
    const float* W4 = (const float*)d_in[9];
    const float* b4 = (const float*)d_in[10];
    const int Nn = in_sizes[0] / 128;   // 50000
    const int E  = in_sizes[1] / 2;     // 800000
    const int* src = ei;
    const int* dst = ei + E;

    char* ws = (char*)d_ws;
    size_t off = 0;
    auto alloc = [&](size_t bytes) -> void* {
        void* p = ws + off;
        off += (bytes + 255) & ~(size_t)255;
        return p;
    };
    float*          deg  = (float*)alloc((size_t)Nn * 4);            // deg -> dinv (in place)
    float*          nrm  = (float*)alloc((size_t)E * 4);
    unsigned short* W1t  = (unsigned short*)alloc(512 * 128 * 2);
    unsigned short* W2t  = (unsigned short*)alloc(128 * 512 * 2);
    unsigned short* W3t  = (unsigned short*)alloc(1024 * 128 * 2);
    unsigned short* W4t  = (unsigned short*)alloc(64 * 1024 * 2);
    float*          agg  = (float*)alloc((size_t)Nn * 128 * 4);      // agg1 then agg2
    unsigned short* actb = (unsigned short*)alloc((size_t)Nn * 128 * 2); // bf16(agg1) then bf16(h2)
    float*          t2   = (float*)alloc((size_t)Nn * 128 * 4);
    unsigned short* h1b  = (unsigned short*)alloc((size_t)Nn * 1024 * 2); // h1b(512) then h3b(1024)
    unsigned short* h3b  = h1b;
    float*          out  = (float*)d_out;

    // normalization factors
    k_fill1<<<cdiv(Nn, 256), 256, 0, stream>>>(deg, Nn);
    k_degacc<<<cdiv(E, 256), 256, 0, stream>>>(dst, ew, deg, E);
    k_rsqrt<<<cdiv(Nn, 256), 256, 0, stream>>>(deg, Nn);              // deg := dinv
    k_norm<<<cdiv(E, 256), 256, 0, stream>>>(src, dst, ew, deg, nrm, E);

    // weights -> bf16 transposed
    k_transpose_f2b<<<cdiv(128 * 512, 256), 256, 0, stream>>>(W1, W1t, 128, 512);
    k_transpose_f2b<<<cdiv(512 * 128, 256), 256, 0, stream>>>(W2, W2t, 512, 128);
    k_transpose_f2b<<<cdiv(128 * 1024, 256), 256, 0, stream>>>(W3, W3t, 128, 1024);
    k_transpose_f2b<<<cdiv(1024 * 64, 256), 256, 0, stream>>>(W4, W4t, 1024, 64);

    // layer 1: aggregate x, then GEMM 128->512 with bias+relu, bf16 out
    k_agg_init<<<cdiv(Nn * 32, 256), 256, 0, stream>>>(x, deg, agg, Nn * 32);
    k_scatter<<<cdiv(E * 32, 256), 256, 0, stream>>>(x, src, dst, nrm, agg, E);
    k_f2b<<<cdiv(Nn * 128, 256), 256, 0, stream>>>(agg, actb, Nn * 128);
    gemm_bt<2, 2, true, true, true><<<dim3(4, cdiv(Nn, 128)), 256, 0, stream>>>(
        actb, W1t, b1, h1b, Nn, 512, 128);

    // layer 2: t2 = h1 @ W2 (fp32 out), aggregate, bias+relu -> bf16
    gemm_bt<2, 2, false, false, false><<<dim3(1, cdiv(Nn, 128)), 256, 0, stream>>>(
        h1b, W2t, nullptr, t2, Nn, 128, 512);
    k_agg_init<<<cdiv(Nn * 32, 256), 256, 0, stream>>>(t2, deg, agg, Nn * 32);
    k_scatter<<<cdiv(E * 32, 256), 256, 0, stream>>>(t2, src, dst, nrm, agg, E);
    k_bias_relu_f2b<<<cdiv(Nn * 128, 256), 256, 0, stream>>>(agg, b2, actb, Nn * 128);

    // layer 3: h3 = relu(h2 @ W3 + b3), bf16 out
    gemm_bt<2, 2, true, true, true><<<dim3(8, cdiv(Nn, 128)), 256, 0, stream>>>(
        actb, W3t, b3, h3b, Nn, 1024, 128);

    // layer 4: out = relu(h3 @ W4 + b4), fp32 out
    gemm_bt<2, 1, true, true, false><<<dim3(1, cdiv(Nn, 128)), 128, 0, stream>>>(
        h3b, W4t, b4, out, Nn, 64, 1024);
}

// Round 2
// 628.672 us; speedup vs baseline: 4.8400x; 4.8400x over previous
//
#include <hip/hip_runtime.h>

// MultiLayerGCN on MI355X — round 2: CSR gather aggregation (no fp32 atomics).
// Math: h1 = relu((Anorm@x) @ W1 + b1)        [aggregate 128 feats, then GEMM]
//       t2 = h1 @ W2;  h2 = relu(Anorm@t2 + b2)
//       h3 = relu(h2 @ W3 + b3); out = relu(h3 @ W4 + b4)
// Anorm@y [dst] = sum_{e: dst(e)=dst} nrm[e]*y[src(e)]  +  y[dst]*dinv[dst]^2
// CSR built per call: hist -> scan -> cursor fill (sorted_src, sorted_nrm).

typedef short bf16x8 __attribute__((ext_vector_type(8)));
typedef float f32x4 __attribute__((ext_vector_type(4)));

__device__ __forceinline__ unsigned short f2b(float f) {
    unsigned u = __builtin_bit_cast(unsigned, f);
    unsigned r = (u + 0x7FFFu + ((u >> 16) & 1u)) >> 16;
    return (unsigned short)r;
}

__global__ void k_zero_int(int* p, int n) {
    int i = blockIdx.x * 256 + threadIdx.x;
    if (i < n) p[i] = 0;
}

__global__ void k_fill1(float* p, int n) {
    int i = blockIdx.x * 256 + threadIdx.x;
    if (i < n) p[i] = 1.0f;
}

// cnt[d]++ (int) and deg[d]+=w (float) in one pass over edges
__global__ void k_hist(const int* __restrict__ dst, const float* __restrict__ w,
                       int* __restrict__ cnt, float* __restrict__ deg, int E) {
    int i = blockIdx.x * 256 + threadIdx.x;
    if (i < E) {
        int d = dst[i];
        atomicAdd(&cnt[d], 1);
        atomicAdd(&deg[d], w[i]);
    }
}

__global__ void k_rsqrt(float* p, int n) {
    int i = blockIdx.x * 256 + threadIdx.x;
    if (i < n) p[i] = rsqrtf(p[i]);
}

__device__ __forceinline__ int wave_iscan(int v, int lane) {
    int s = v;
    #pragma unroll
    for (int d = 1; d < 64; d <<= 1) {
        int t = __shfl_up(s, d);
        if (lane >= d) s += t;
    }
    return s;
}

// single-block exclusive scan of cnt[0..n) -> off[0..n], off[n]=total. 1024 threads.
__global__ void k_scan(const int* __restrict__ cnt, int* __restrict__ off, int n) {
    __shared__ int wsum[17];
    __shared__ int carry;
    const int tid = threadIdx.x, lane = tid & 63, wid = tid >> 6;
    if (tid == 0) carry = 0;
    __syncthreads();
    for (int base = 0; base < n; base += 1024) {
        int i = base + tid;
        int v = (i < n) ? cnt[i] : 0;
        int s = wave_iscan(v, lane);
        if (lane == 63) wsum[wid] = s;
        __syncthreads();
        if (tid < 16) {
            int ws = wsum[tid];
            int sc = ws;
            #pragma unroll
            for (int k = 1; k < 16; k <<= 1) {
                int t = __shfl_up(sc, k);
                if (tid >= k) sc += t;
            }
            wsum[tid] = sc - ws;          // exclusive wave offset
            if (tid == 15) wsum[16] = sc; // chunk total
        }
        __syncthreads();
        int o = carry + wsum[wid] + s - v;
        if (i < n) off[i] = o;
        int tot = wsum[16];
        __syncthreads();
        if (tid == 0) carry += tot;
        __syncthreads();
    }
    if (threadIdx.x == 0) off[n] = carry;
}

__global__ void k_copy_int(const int* __restrict__ a, int* __restrict__ b, int n) {
    int i = blockIdx.x * 256 + threadIdx.x;
    if (i < n) b[i] = a[i];
}

// place each edge into its dst's CSR slot; nrm computed here
__global__ void k_fill_csr(const int* __restrict__ src, const int* __restrict__ dst,
                           const float* __restrict__ w, const float* __restrict__ dinv,
                           int* __restrict__ cursor, int* __restrict__ s_src,
                           float* __restrict__ s_nrm, int E) {
    int e = blockIdx.x * 256 + threadIdx.x;
    if (e >= E) return;
    int d = dst[e], s = src[e];
    int slot = atomicAdd(&cursor[d], 1);
    s_src[slot] = s;
    s_nrm[slot] = dinv[s] * w[e] * dinv[d];
}

// one wave per node: out_bf16[node,:] = (opt bias+relu)( sum_e nrm*X[src] + X[node]*dinv^2 )
template <bool BIAS_RELU>
__global__ __launch_bounds__(256) void k_gather_agg(
    const float* __restrict__ X, const int* __restrict__ off,
    const int* __restrict__ s_src, const float* __restrict__ s_nrm,
    const float* __restrict__ dinv, const float* __restrict__ bias,
    unsigned short* __restrict__ outb, int Nn) {
    int node = blockIdx.x * 4 + (threadIdx.x >> 6);
    if (node >= Nn) return;
    int lane = threadIdx.x & 63;
    float di = dinv[node]; di *= di;
    float2 v = ((const float2*)(X + (size_t)node * 128))[lane];
    float ax = v.x * di, ay = v.y * di;
    int beg = off[node], end = off[node + 1];
    for (int j = beg; j < end; ++j) {
        int s = s_src[j];
        float nv = s_nrm[j];
        float2 xv = ((const float2*)(X + (size_t)s * 128))[lane];
        ax += nv * xv.x;
        ay += nv * xv.y;
    }
    if (BIAS_RELU) {
        float2 bv = ((const float2*)bias)[lane];
        ax = fmaxf(ax + bv.x, 0.0f);
        ay = fmaxf(ay + bv.y, 0.0f);
    }
    ushort2 o; o.x = f2b(ax); o.y = f2b(ay);
    ((ushort2*)(outb + (size_t)node * 128))[lane] = o;
}

// W [K,N] fp32 -> Wt [N,K] bf16
__global__ void k_transpose_f2b(const float* __restrict__ W, unsigned short* __restrict__ Wt,
                                int K, int N) {
    int i = blockIdx.x * 256 + threadIdx.x;
    if (i >= K * N) return;
    int k = i / N, n = i % N;
    Wt[(size_t)n * K + k] = f2b(W[i]);
}

// C[M,N] = A[M,K] @ Bt[N,K]^T  (both bf16, row-major), fp32 accumulate.
// Wave tile 64x64 (4x4 MFMA 16x16x32), block = WR x WC waves.
template <int WR, int WC, bool HAS_BIAS, bool RELU, bool OUT_BF16>
__global__ __launch_bounds__(WR * WC * 64) void gemm_bt(
    const unsigned short* __restrict__ A, const unsigned short* __restrict__ Bt,
    const float* __restrict__ bias, void* __restrict__ C, int M, int N, int K) {
    constexpr int BM = WR * 64, BN = WC * 64, NT = WR * WC * 64;
    __shared__ __align__(16) unsigned short As[BM * 32];
    __shared__ __align__(16) unsigned short Bs[BN * 32];
    const int tid = threadIdx.x;
    const int wave = tid >> 6, lane = tid & 63;
    const int wr = wave / WC, wc = wave % WC;
    const int lm = lane & 15, quad = lane >> 4;
    const int bm0 = blockIdx.y * BM, bn0 = blockIdx.x * BN;

    f32x4 acc[4][4] = {};

    const int nkb = K >> 5;
    for (int kb = 0; kb < nkb; ++kb) {
        #pragma unroll
        for (int c = tid; c < BM * 4; c += NT) {
            int r = c >> 2, cc = c & 3;
            int gm = bm0 + r;
            int4 v = make_int4(0, 0, 0, 0);
            if (gm < M) v = *(const int4*)(A + (size_t)gm * K + kb * 32 + cc * 8);
            *(int4*)&As[r * 32 + cc * 8] = v;
        }
        #pragma unroll
        for (int c = tid; c < BN * 4; c += NT) {
            int r = c >> 2, cc = c & 3;
            int gn = bn0 + r;
            *(int4*)&Bs[r * 32 + cc * 8] =
                *(const int4*)(Bt + (size_t)gn * K + kb * 32 + cc * 8);
        }
        __syncthreads();
        bf16x8 af[4], bfr[4];
        #pragma unroll
        for (int i = 0; i < 4; i++)
            af[i] = *(const bf16x8*)&As[(wr * 64 + i * 16 + lm) * 32 + quad * 8];
        #pragma unroll
        for (int j = 0; j < 4; j++)
            bfr[j] = *(const bf16x8*)&Bs[(wc * 64 + j * 16 + lm) * 32 + quad * 8];
        #pragma unroll
        for (int i = 0; i < 4; i++)
            #pragma unroll
            for (int j = 0; j < 4; j++)
                acc[i][j] = __builtin_amdgcn_mfma_f32_16x16x32_bf16(af[i], bfr[j], acc[i][j], 0, 0, 0);
        __syncthreads();
    }

    #pragma unroll
    for (int i = 0; i < 4; i++) {
        int mbase = bm0 + wr * 64 + i * 16 + quad * 4;
        #pragma unroll
        for (int j = 0; j < 4; j++) {
            int col = bn0 + wc * 64 + j * 16 + lm;
            float bv = HAS_BIAS ? bias[col] : 0.0f;
            f32x4 v = acc[i][j];
            #pragma unroll
            for (int r = 0; r < 4; r++) {
                int m = mbase + r;
                if (m < M) {
                    float o = v[r] + bv;
                    if (RELU) o = fmaxf(o, 0.0f);
                    if (OUT_BF16)
                        ((unsigned short*)C)[(size_t)m * N + col] = f2b(o);
                    else
                        ((float*)C)[(size_t)m * N + col] = o;
                }
            }
        }
    }
}

static inline int cdiv(long a, long b) { return (int)((a + b - 1) / b); }

extern "C" void kernel_launch(void* const* d_in, const int* in_sizes, int n_in,
                              void* d_out, int out_size, void* d_ws, size_t ws_size,
                              hipStream_t stream) {
    const float* x  = (const float*)d_in[0];
    const int*   ei = (const int*)d_in[1];
    const float* ew = (const float*)d_in[2];
    const float* W1 = (const float*)d_in[3];
    const float* b1 = (const float*)d_in[4];
    const float* W2 = (const float*)d_in[5];
    const float* b2 = (const float*)d_in[6];
    const float* W3 = (const float*)d_in[7];
    const float* b3 = (const float*)d_in[8];
    const float* W4 = (const float*)d_in[9];
    const float* b4 = (const float*)d_in[10];
    const int Nn = in_sizes[0] / 128;   // 50000
    const int E  = in_sizes[1] / 2;     // 800000
    const int* src = ei;
    const int* dst = ei + E;

    char* ws = (char*)d_ws;
    size_t off_b = 0;
    auto alloc = [&](size_t bytes) -> void* {
        void* p = ws + off_b;
        off_b += (bytes + 255) & ~(size_t)255;
        return p;
    };
    float*          deg    = (float*)alloc((size_t)Nn * 4);          // deg -> dinv in place
    int*            cnt    = (int*)alloc((size_t)Nn * 4);
    int*            off    = (int*)alloc((size_t)(Nn + 1) * 4);
    int*            cursor = (int*)alloc((size_t)Nn * 4);
    int*            s_src  = (int*)alloc((size_t)E * 4);
    float*          s_nrm  = (float*)alloc((size_t)E * 4);
    unsigned short* W1t    = (unsigned short*)alloc(512 * 128 * 2);
    unsigned short* W2t    = (unsigned short*)alloc(128 * 512 * 2);
    unsigned short* W3t    = (unsigned short*)alloc(1024 * 128 * 2);
    unsigned short* W4t    = (unsigned short*)alloc(64 * 1024 * 2);
    unsigned short* actb   = (unsigned short*)alloc((size_t)Nn * 128 * 2); // bf16 agg out
    float*          t2     = (float*)alloc((size_t)Nn * 128 * 4);
    unsigned short* h1b    = (unsigned short*)alloc((size_t)Nn * 1024 * 2); // h1(512) / h3(1024)
    unsigned short* h3b    = h1b;
    float*          out    = (float*)d_out;

    // degree + CSR build
    k_zero_int<<<cdiv(Nn, 256), 256, 0, stream>>>(cnt, Nn);
    k_fill1<<<cdiv(Nn, 256), 256, 0, stream>>>(deg, Nn);
    k_hist<<<cdiv(E, 256), 256, 0, stream>>>(dst, ew, cnt, deg, E);
    k_rsqrt<<<cdiv(Nn, 256), 256, 0, stream>>>(deg, Nn);   // deg := dinv
    k_scan<<<1, 1024, 0, stream>>>(cnt, off, Nn);
    k_copy_int<<<cdiv(Nn, 256), 256, 0, stream>>>(off, cursor, Nn);
    k_fill_csr<<<cdiv(E, 256), 256, 0, stream>>>(src, dst, ew, deg, cursor, s_src, s_nrm, E);

    // weights -> bf16 transposed
    k_transpose_f2b<<<cdiv(128 * 512, 256), 256, 0, stream>>>(W1, W1t, 128, 512);
    k_transpose_f2b<<<cdiv(512 * 128, 256), 256, 0, stream>>>(W2, W2t, 512, 128);
    k_transpose_f2b<<<cdiv(128 * 1024, 256), 256, 0, stream>>>(W3, W3t, 128, 1024);
    k_transpose_f2b<<<cdiv(1024 * 64, 256), 256, 0, stream>>>(W4, W4t, 1024, 64);

    // layer 1: aggregate x (gather, no bias/relu) -> bf16, then GEMM 128->512 +bias+relu
    k_gather_agg<false><<<cdiv(Nn, 4), 256, 0, stream>>>(
        x, off, s_src, s_nrm, deg, nullptr, actb, Nn);
    gemm_bt<2, 2, true, true, true><<<dim3(4, cdiv(Nn, 128)), 256, 0, stream>>>(
        actb, W1t, b1, h1b, Nn, 512, 128);

    // layer 2: t2 = h1 @ W2 (fp32 out), aggregate +bias+relu -> bf16
    gemm_bt<2, 2, false, false, false><<<dim3(1, cdiv(Nn, 128)), 256, 0, stream>>>(
        h1b, W2t, nullptr, t2, Nn, 128, 512);
    k_gather_agg<true><<<cdiv(Nn, 4), 256, 0, stream>>>(
        t2, off, s_src, s_nrm, deg, b2, actb, Nn);

    // layer 3: h3 = relu(h2 @ W3 + b3), bf16 out
    gemm_bt<2, 2, true, true, true><<<dim3(8, cdiv(Nn, 128)), 256, 0, stream>>>(
        actb, W3t, b3, h3b, Nn, 1024, 128);

    // layer 4: out = relu(h3 @ W4 + b4), fp32 out
    gemm_bt<2, 1, true, true, false><<<dim3(1, cdiv(Nn, 128)), 128, 0, stream>>>(
        h3b, W4t, b4, out, Nn, 64, 1024);
}

// Round 3
// 510.480 us; speedup vs baseline: 5.9606x; 1.2315x over previous
//
#include <hip/hip_runtime.h>

// MultiLayerGCN on MI355X — round 3: bf16 gather (half bytes), split-K G4,
// merged setup kernels.
// Math: h1 = relu((Anorm@x) @ W1 + b1)
//       t2 = h1 @ W2 (bf16);  h2 = relu(Anorm@t2 + b2)
//       h3 = relu(h2 @ W3 + b3); out = relu(h3 @ W4 + b4)
// Anorm@y [d] = sum_{e: dst=d} nrm[e]*y[src(e)] + y[d]*dinv[d]^2

typedef short bf16x8 __attribute__((ext_vector_type(8)));
typedef float f32x4 __attribute__((ext_vector_type(4)));

__device__ __forceinline__ unsigned short f2b(float f) {
    unsigned u = __builtin_bit_cast(unsigned, f);
    unsigned r = (u + 0x7FFFu + ((u >> 16) & 1u)) >> 16;
    return (unsigned short)r;
}
__device__ __forceinline__ float b2f(unsigned short u) {
    return __builtin_bit_cast(float, (unsigned)u << 16);
}

__global__ void k_init(int* __restrict__ cnt, float* __restrict__ deg, int n) {
    int i = blockIdx.x * 256 + threadIdx.x;
    if (i < n) { cnt[i] = 0; deg[i] = 1.0f; }
}

// cnt[d]++ (int) and deg[d]+=w (float) in one pass over edges
__global__ void k_hist(const int* __restrict__ dst, const float* __restrict__ w,
                       int* __restrict__ cnt, float* __restrict__ deg, int E) {
    int i = blockIdx.x * 256 + threadIdx.x;
    if (i < E) {
        int d = dst[i];
        atomicAdd(&cnt[d], 1);
        atomicAdd(&deg[d], w[i]);
    }
}

__global__ void k_rsqrt(float* p, int n) {
    int i = blockIdx.x * 256 + threadIdx.x;
    if (i < n) p[i] = rsqrtf(p[i]);
}

__device__ __forceinline__ int wave_iscan(int v, int lane) {
    int s = v;
    #pragma unroll
    for (int d = 1; d < 64; d <<= 1) {
        int t = __shfl_up(s, d);
        if (lane >= d) s += t;
    }
    return s;
}

// single-block exclusive scan, 4 elems/thread; writes off[0..n] and cursor[0..n)
__global__ void k_scan4(const int* __restrict__ cnt, int* __restrict__ off,
                        int* __restrict__ cursor, int n) {
    __shared__ int wsum[17];
    __shared__ int carry;
    const int tid = threadIdx.x, lane = tid & 63, wid = tid >> 6;
    if (tid == 0) carry = 0;
    __syncthreads();
    for (int base = 0; base < n; base += 4096) {
        int i0 = base + tid * 4;
        int v[4];
        #pragma unroll
        for (int k = 0; k < 4; k++) v[k] = (i0 + k < n) ? cnt[i0 + k] : 0;
        int tsum = v[0] + v[1] + v[2] + v[3];
        int s = wave_iscan(tsum, lane);       // inclusive over thread sums
        if (lane == 63) wsum[wid] = s;
        __syncthreads();
        if (tid < 16) {
            int ws = wsum[tid];
            int sc = ws;
            #pragma unroll
            for (int k = 1; k < 16; k <<= 1) {
                int t = __shfl_up(sc, k);
                if (tid >= k) sc += t;
            }
            wsum[tid] = sc - ws;              // exclusive wave offset
            if (tid == 15) wsum[16] = sc;     // chunk total
        }
        __syncthreads();
        int pre = carry + wsum[wid] + s - tsum;
        #pragma unroll
        for (int k = 0; k < 4; k++) {
            if (i0 + k < n) { off[i0 + k] = pre; cursor[i0 + k] = pre; }
            pre += v[k];
        }
        int tot = wsum[16];
        __syncthreads();
        if (tid == 0) carry += tot;
        __syncthreads();
    }
    if (tid == 0) off[n] = carry;
}

// place each edge into its dst's CSR slot; record = (src, bits(nrm))
__global__ void k_fill_csr(const int* __restrict__ src, const int* __restrict__ dst,
                           const float* __restrict__ w, const float* __restrict__ dinv,
                           int* __restrict__ cursor, int2* __restrict__ s_edge, int E) {
    int e = blockIdx.x * 256 + threadIdx.x;
    if (e >= E) return;
    int d = dst[e], s = src[e];
    int slot = atomicAdd(&cursor[d], 1);
    float nv = dinv[s] * w[e] * dinv[d];
    s_edge[slot] = make_int2(s, __builtin_bit_cast(int, nv));
}

// fp32 -> bf16, 4 elems/thread
__global__ void k_f2b4(const float* __restrict__ in, unsigned short* __restrict__ out, int n4) {
    int i = blockIdx.x * 256 + threadIdx.x;
    if (i >= n4) return;
    float4 v = ((const float4*)in)[i];
    ushort4 o;
    o.x = f2b(v.x); o.y = f2b(v.y); o.z = f2b(v.z); o.w = f2b(v.w);
    ((ushort4*)out)[i] = o;
}

// all 4 weight transposes fp32[K,N] -> bf16[N,K] in one kernel
__global__ void k_wt_all(const float* __restrict__ W1, const float* __restrict__ W2,
                         const float* __restrict__ W3, const float* __restrict__ W4,
                         unsigned short* __restrict__ W1t, unsigned short* __restrict__ W2t,
                         unsigned short* __restrict__ W3t, unsigned short* __restrict__ W4t) {
    int i = blockIdx.x * 256 + threadIdx.x;
    if (i < 65536) {                       // W1: 128x512
        int k = i >> 9, n = i & 511;
        W1t[n * 128 + k] = f2b(W1[i]);
    } else if (i < 131072) {               // W2: 512x128
        int j = i - 65536; int k = j >> 7, n = j & 127;
        W2t[n * 512 + k] = f2b(W2[j]);
    } else if (i < 262144) {               // W3: 128x1024
        int j = i - 131072; int k = j >> 10, n = j & 1023;
        W3t[n * 128 + k] = f2b(W3[j]);
    } else {                               // W4: 1024x64
        int j = i - 262144; int k = j >> 6, n = j & 63;
        W4t[n * 1024 + k] = f2b(W4[j]);
    }
}

// one wave per node, bf16 input rows (256B), fp32 accum, bf16 out.
template <bool BIAS_RELU>
__global__ __launch_bounds__(256) void k_gather_agg(
    const unsigned short* __restrict__ Xb, const int* __restrict__ off,
    const int2* __restrict__ s_edge, const float* __restrict__ dinv,
    const float* __restrict__ bias, unsigned short* __restrict__ outb, int Nn) {
    int node = blockIdx.x * 4 + (threadIdx.x >> 6);
    if (node >= Nn) return;
    int lane = threadIdx.x & 63;
    float di = dinv[node]; di *= di;
    ushort2 sv = ((const ushort2*)(Xb + (size_t)node * 128))[lane];
    float ax = b2f(sv.x) * di, ay = b2f(sv.y) * di;
    int beg = off[node], end = off[node + 1];
    int j = beg;
    for (; j + 4 <= end; j += 4) {
        int2 e0 = s_edge[j], e1 = s_edge[j + 1], e2 = s_edge[j + 2], e3 = s_edge[j + 3];
        ushort2 r0 = ((const ushort2*)(Xb + (size_t)e0.x * 128))[lane];
        ushort2 r1 = ((const ushort2*)(Xb + (size_t)e1.x * 128))[lane];
        ushort2 r2 = ((const ushort2*)(Xb + (size_t)e2.x * 128))[lane];
        ushort2 r3 = ((const ushort2*)(Xb + (size_t)e3.x * 128))[lane];
        float n0 = __builtin_bit_cast(float, e0.y), n1 = __builtin_bit_cast(float, e1.y);
        float n2 = __builtin_bit_cast(float, e2.y), n3 = __builtin_bit_cast(float, e3.y);
        ax += n0 * b2f(r0.x) + n1 * b2f(r1.x) + n2 * b2f(r2.x) + n3 * b2f(r3.x);
        ay += n0 * b2f(r0.y) + n1 * b2f(r1.y) + n2 * b2f(r2.y) + n3 * b2f(r3.y);
    }
    for (; j < end; ++j) {
        int2 e = s_edge[j];
        float nv = __builtin_bit_cast(float, e.y);
        ushort2 r = ((const ushort2*)(Xb + (size_t)e.x * 128))[lane];
        ax += nv * b2f(r.x);
        ay += nv * b2f(r.y);
    }
    if (BIAS_RELU) {
        float2 bv = ((const float2*)bias)[lane];
        ax = fmaxf(ax + bv.x, 0.0f);
        ay = fmaxf(ay + bv.y, 0.0f);
    }
    ushort2 o; o.x = f2b(ax); o.y = f2b(ay);
    ((ushort2*)(outb + (size_t)node * 128))[lane] = o;
}

// C[M,N] = A[M,K] @ Bt[N,K]^T (bf16, row-major), fp32 accum.
// Wave tile 64x64 (4x4 MFMA 16x16x32). kb_per: k-blocks per z-slice (split-K);
// fp32 output goes to C + z*M*N.
template <int WR, int WC, bool HAS_BIAS, bool RELU, bool OUT_BF16>
__global__ __launch_bounds__(WR * WC * 64) void gemm_bt(
    const unsigned short* __restrict__ A, const unsigned short* __restrict__ Bt,
    const float* __restrict__ bias, void* __restrict__ C, int M, int N, int K, int kb_per) {
    constexpr int BM = WR * 64, BN = WC * 64, NT = WR * WC * 64;
    __shared__ __align__(16) unsigned short As[BM * 32];
    __shared__ __align__(16) unsigned short Bs[BN * 32];
    const int tid = threadIdx.x;
    const int wave = tid >> 6, lane = tid & 63;
    const int wr = wave / WC, wc = wave % WC;
    const int lm = lane & 15, quad = lane >> 4;
    const int bm0 = blockIdx.y * BM, bn0 = blockIdx.x * BN;

    f32x4 acc[4][4] = {};

    const int nkb = K >> 5;
    const int kb0 = blockIdx.z * kb_per;
    const int kb1 = min(kb0 + kb_per, nkb);
    for (int kb = kb0; kb < kb1; ++kb) {
        #pragma unroll
        for (int c = tid; c < BM * 4; c += NT) {
            int r = c >> 2, cc = c & 3;
            int gm = bm0 + r;
            int4 v = make_int4(0, 0, 0, 0);
            if (gm < M) v = *(const int4*)(A + (size_t)gm * K + kb * 32 + cc * 8);
            *(int4*)&As[r * 32 + cc * 8] = v;
        }
        #pragma unroll
        for (int c = tid; c < BN * 4; c += NT) {
            int r = c >> 2, cc = c & 3;
            int gn = bn0 + r;
            *(int4*)&Bs[r * 32 + cc * 8] =
                *(const int4*)(Bt + (size_t)gn * K + kb * 32 + cc * 8);
        }
        __syncthreads();
        bf16x8 af[4], bfr[4];
        #pragma unroll
        for (int i = 0; i < 4; i++)
            af[i] = *(const bf16x8*)&As[(wr * 64 + i * 16 + lm) * 32 + quad * 8];
        #pragma unroll
        for (int j = 0; j < 4; j++)
            bfr[j] = *(const bf16x8*)&Bs[(wc * 64 + j * 16 + lm) * 32 + quad * 8];
        #pragma unroll
        for (int i = 0; i < 4; i++)
            #pragma unroll
            for (int j = 0; j < 4; j++)
                acc[i][j] = __builtin_amdgcn_mfma_f32_16x16x32_bf16(af[i], bfr[j], acc[i][j], 0, 0, 0);
        __syncthreads();
    }

    float* Cf = (float*)C + (size_t)blockIdx.z * M * N;
    #pragma unroll
    for (int i = 0; i < 4; i++) {
        int mbase = bm0 + wr * 64 + i * 16 + quad * 4;
        #pragma unroll
        for (int j = 0; j < 4; j++) {
            int col = bn0 + wc * 64 + j * 16 + lm;
            float bv = HAS_BIAS ? bias[col] : 0.0f;
            f32x4 v = acc[i][j];
            #pragma unroll
            for (int r = 0; r < 4; r++) {
                int m = mbase + r;
                if (m < M) {
                    float o = v[r] + bv;
                    if (RELU) o = fmaxf(o, 0.0f);
                    if (OUT_BF16)
                        ((unsigned short*)C)[(size_t)m * N + col] = f2b(o);
                    else
                        Cf[(size_t)m * N + col] = o;
                }
            }
        }
    }
}

// out = relu(part0 + part1 + bias), N=64 cols, float4 per thread
__global__ void k_reduce2(const float* __restrict__ part, const float* __restrict__ bias,
                          float* __restrict__ out, int n4) {
    int i = blockIdx.x * 256 + threadIdx.x;
    if (i >= n4) return;
    float4 a = ((const float4*)part)[i];
    float4 b = ((const float4*)part)[i + n4];
    float4 bv = ((const float4*)bias)[i & 15];
    float4 o;
    o.x = fmaxf(a.x + b.x + bv.x, 0.0f);
    o.y = fmaxf(a.y + b.y + bv.y, 0.0f);
    o.z = fmaxf(a.z + b.z + bv.z, 0.0f);
    o.w = fmaxf(a.w + b.w + bv.w, 0.0f);
    ((float4*)out)[i] = o;
}

static inline int cdiv(long a, long b) { return (int)((a + b - 1) / b); }

extern "C" void kernel_launch(void* const* d_in, const int* in_sizes, int n_in,
                              void* d_out, int out_size, void* d_ws, size_t ws_size,
                              hipStream_t stream) {
    const float* x  = (const float*)d_in[0];
    const int*   ei = (const int*)d_in[1];
    const float* ew = (const float*)d_in[2];
    const float* W1 = (const float*)d_in[3];
    const float* b1 = (const float*)d_in[4];
    const float* W2 = (const float*)d_in[5];
    const float* b2 = (const float*)d_in[6];
    const float* W3 = (const float*)d_in[7];
    const float* b3 = (const float*)d_in[8];
    const float* W4 = (const float*)d_in[9];
    const float* b4 = (const float*)d_in[10];
    const int Nn = in_sizes[0] / 128;   // 50000
    const int E  = in_sizes[1] / 2;     // 800000
    const int* src = ei;
    const int* dst = ei + E;

    char* ws = (char*)d_ws;
    size_t off_b = 0;
    auto alloc = [&](size_t bytes) -> void* {
        void* p = ws + off_b;
        off_b += (bytes + 255) & ~(size_t)255;
        return p;
    };
    float*          deg    = (float*)alloc((size_t)Nn * 4);           // deg -> dinv
    int*            cnt    = (int*)alloc((size_t)Nn * 4);
    int*            off    = (int*)alloc((size_t)(Nn + 1) * 4);
    int*            cursor = (int*)alloc((size_t)Nn * 4);
    int2*           s_edge = (int2*)alloc((size_t)E * 8);
    unsigned short* W1t    = (unsigned short*)alloc(512 * 128 * 2);
    unsigned short* W2t    = (unsigned short*)alloc(128 * 512 * 2);
    unsigned short* W3t    = (unsigned short*)alloc(1024 * 128 * 2);
    unsigned short* W4t    = (unsigned short*)alloc(64 * 1024 * 2);
    unsigned short* xb     = (unsigned short*)alloc((size_t)Nn * 128 * 2); // bf16(x); part slab0
    unsigned short* t2b    = (unsigned short*)alloc((size_t)Nn * 128 * 2); // bf16 t2; part slab1
    unsigned short* actb   = (unsigned short*)alloc((size_t)Nn * 128 * 2); // agg out (bf16)
    unsigned short* h1b    = (unsigned short*)alloc((size_t)Nn * 1024 * 2); // h1(512)/h3(1024)
    unsigned short* h3b    = h1b;
    float*          part   = (float*)xb;   // 2*Nn*64 fp32 = 25.6MB overlays xb+t2b (free by layer 4)
    float*          out    = (float*)d_out;

    // degree + CSR build
    k_init<<<cdiv(Nn, 256), 256, 0, stream>>>(cnt, deg, Nn);
    k_hist<<<cdiv(E, 256), 256, 0, stream>>>(dst, ew, cnt, deg, E);
    k_rsqrt<<<cdiv(Nn, 256), 256, 0, stream>>>(deg, Nn);   // deg := dinv
    k_scan4<<<1, 1024, 0, stream>>>(cnt, off, cursor, Nn);
    k_fill_csr<<<cdiv(E, 256), 256, 0, stream>>>(src, dst, ew, deg, cursor, s_edge, E);

    // weights -> bf16 transposed (one kernel), x -> bf16
    k_wt_all<<<1280, 256, 0, stream>>>(W1, W2, W3, W4, W1t, W2t, W3t, W4t);
    k_f2b4<<<cdiv((size_t)Nn * 32, 256), 256, 0, stream>>>(x, xb, Nn * 32);

    // layer 1: aggregate x_bf16 -> actb, GEMM 128->512 +bias+relu -> h1b
    k_gather_agg<false><<<cdiv(Nn, 4), 256, 0, stream>>>(
        xb, off, s_edge, deg, nullptr, actb, Nn);
    gemm_bt<2, 2, true, true, true><<<dim3(4, cdiv(Nn, 128)), 256, 0, stream>>>(
        actb, W1t, b1, h1b, Nn, 512, 128, 4);

    // layer 2: t2 = h1 @ W2 (bf16 out), aggregate +bias+relu -> actb
    gemm_bt<1, 2, false, false, true><<<dim3(1, cdiv(Nn, 64)), 128, 0, stream>>>(
        h1b, W2t, nullptr, t2b, Nn, 128, 512, 16);
    k_gather_agg<true><<<cdiv(Nn, 4), 256, 0, stream>>>(
        t2b, off, s_edge, deg, b2, actb, Nn);

    // layer 3: h3 = relu(h2 @ W3 + b3) -> h3b
    gemm_bt<2, 2, true, true, true><<<dim3(8, cdiv(Nn, 128)), 256, 0, stream>>>(
        actb, W3t, b3, h3b, Nn, 1024, 128, 4);

    // layer 4: split-K=2 partials (fp32, overlays xb/t2b), then reduce+bias+relu
    gemm_bt<2, 1, false, false, false><<<dim3(1, cdiv(Nn, 128), 2), 128, 0, stream>>>(
        h3b, W4t, nullptr, part, Nn, 64, 1024, 16);
    k_reduce2<<<cdiv(Nn * 16, 256), 256, 0, stream>>>(part, b4, out, Nn * 16);
}

// Round 4
// 397.338 us; speedup vs baseline: 7.6579x; 1.2848x over previous
//
#include <hip/hip_runtime.h>

// MultiLayerGCN on MI355X — round 4: ELL aggregation structure (1 atomic/edge),
// shuffle-broadcast gather loop, nrm folded into gather-1.
// Math: h1 = relu((Anorm@x) @ W1 + b1)
//       t2 = h1 @ W2 (bf16);  h2 = relu(Anorm@t2 + b2)
//       h3 = relu(h2 @ W3 + b3); out = relu(h3 @ W4 + b4)
// Anorm@y [d] = sum_{e: dst=d} nrm[e]*y[src(e)] + y[d]*dinv[d]^2
// ELL: 64 slots/node (deg ~ Poisson(16), P(overflow) ~ 1e-13; guarded).

#define ELLW 64

typedef short bf16x8 __attribute__((ext_vector_type(8)));
typedef float f32x4 __attribute__((ext_vector_type(4)));

__device__ __forceinline__ unsigned short f2b(float f) {
    unsigned u = __builtin_bit_cast(unsigned, f);
    unsigned r = (u + 0x7FFFu + ((u >> 16) & 1u)) >> 16;
    return (unsigned short)r;
}
__device__ __forceinline__ float b2f(unsigned short u) {
    return __builtin_bit_cast(float, (unsigned)u << 16);
}

__global__ void k_zero_int(int* p, int n) {
    int i = blockIdx.x * 256 + threadIdx.x;
    if (i < n) p[i] = 0;
}

// one atomic per edge: claim slot in dst's ELL row, write (src, w) SoA
__global__ void k_fill_ell(const int* __restrict__ src, const int* __restrict__ dst,
                           const float* __restrict__ w, int* __restrict__ cnt,
                           int* __restrict__ s_src, float* __restrict__ s_w, int E) {
    int e = blockIdx.x * 256 + threadIdx.x;
    if (e >= E) return;
    int d = dst[e];
    int slot = atomicAdd(&cnt[d], 1);
    if (slot < ELLW) {
        size_t idx = (size_t)d * ELLW + slot;
        s_src[idx] = src[e];
        s_w[idx] = w[e];
    }
}

// one wave per node: dinv[node] = rsqrt(1 + sum_j w_j)   (no atomics)
__global__ __launch_bounds__(256) void k_deg(const float* __restrict__ s_w,
                                             const int* __restrict__ cnt,
                                             float* __restrict__ dinv, int Nn) {
    int node = blockIdx.x * 4 + (threadIdx.x >> 6);
    if (node >= Nn) return;
    int lane = threadIdx.x & 63;
    int c = min(cnt[node], ELLW);
    float s = (lane < c) ? s_w[(size_t)node * ELLW + lane] : 0.0f;
    #pragma unroll
    for (int d = 32; d > 0; d >>= 1) s += __shfl_down(s, d);
    if (lane == 0) dinv[node] = rsqrtf(1.0f + s);
}

// fp32 -> bf16, 4 elems/thread
__global__ void k_f2b4(const float* __restrict__ in, unsigned short* __restrict__ out, int n4) {
    int i = blockIdx.x * 256 + threadIdx.x;
    if (i >= n4) return;
    float4 v = ((const float4*)in)[i];
    ushort4 o;
    o.x = f2b(v.x); o.y = f2b(v.y); o.z = f2b(v.z); o.w = f2b(v.w);
    ((ushort4*)out)[i] = o;
}

// all 4 weight transposes fp32[K,N] -> bf16[N,K] in one kernel
__global__ void k_wt_all(const float* __restrict__ W1, const float* __restrict__ W2,
                         const float* __restrict__ W3, const float* __restrict__ W4,
                         unsigned short* __restrict__ W1t, unsigned short* __restrict__ W2t,
                         unsigned short* __restrict__ W3t, unsigned short* __restrict__ W4t) {
    int i = blockIdx.x * 256 + threadIdx.x;
    if (i < 65536) {                       // W1: 128x512
        int k = i >> 9, n = i & 511;
        W1t[n * 128 + k] = f2b(W1[i]);
    } else if (i < 131072) {               // W2: 512x128
        int j = i - 65536; int k = j >> 7, n = j & 127;
        W2t[n * 512 + k] = f2b(W2[j]);
    } else if (i < 262144) {               // W3: 128x1024
        int j = i - 131072; int k = j >> 10, n = j & 1023;
        W3t[n * 128 + k] = f2b(W3[j]);
    } else {                               // W4: 1024x64
        int j = i - 262144; int k = j >> 6, n = j & 63;
        W4t[n * 1024 + k] = f2b(W4[j]);
    }
}

// one wave per node. lane j<c holds edge j's (src, w-or-nrm) in registers;
// inner loop broadcasts via shuffle — zero record loads in the loop.
// FIRST: compute nrm = dinv[src]*w*dinv[node], write back to s_w for pass 2.
template <bool FIRST, bool BIAS_RELU>
__global__ __launch_bounds__(256) void k_gather(
    const unsigned short* __restrict__ Xb, const int* __restrict__ s_src,
    float* __restrict__ s_w, const int* __restrict__ cnt,
    const float* __restrict__ dinv, const float* __restrict__ bias,
    unsigned short* __restrict__ outb, int Nn) {
    int node = blockIdx.x * 4 + (threadIdx.x >> 6);
    if (node >= Nn) return;
    int lane = threadIdx.x & 63;
    float di = dinv[node];
    float dii = di * di;
    ushort2 sv = ((const ushort2*)(Xb + (size_t)node * 128))[lane];
    float ax = b2f(sv.x) * dii, ay = b2f(sv.y) * dii;

    int c = min(cnt[node], ELLW);
    size_t base = (size_t)node * ELLW;
    int sreg = 0;
    float nv = 0.0f;
    if (lane < c) {
        sreg = s_src[base + lane];
        float wv = s_w[base + lane];
        if (FIRST) {
            nv = dinv[sreg] * wv * di;
            s_w[base + lane] = nv;       // pass 2 reads nrm directly
        } else {
            nv = wv;                      // already nrm
        }
    }

    int j = 0;
    for (; j + 4 <= c; j += 4) {
        int s0 = __shfl(sreg, j),     s1 = __shfl(sreg, j + 1);
        int s2 = __shfl(sreg, j + 2), s3 = __shfl(sreg, j + 3);
        float n0 = __shfl(nv, j),     n1 = __shfl(nv, j + 1);
        float n2 = __shfl(nv, j + 2), n3 = __shfl(nv, j + 3);
        ushort2 r0 = ((const ushort2*)(Xb + (size_t)s0 * 128))[lane];
        ushort2 r1 = ((const ushort2*)(Xb + (size_t)s1 * 128))[lane];
        ushort2 r2 = ((const ushort2*)(Xb + (size_t)s2 * 128))[lane];
        ushort2 r3 = ((const ushort2*)(Xb + (size_t)s3 * 128))[lane];
        ax += n0 * b2f(r0.x) + n1 * b2f(r1.x) + n2 * b2f(r2.x) + n3 * b2f(r3.x);
        ay += n0 * b2f(r0.y) + n1 * b2f(r1.y) + n2 * b2f(r2.y) + n3 * b2f(r3.y);
    }
    for (; j < c; ++j) {
        int sj = __shfl(sreg, j);
        float nj = __shfl(nv, j);
        ushort2 r = ((const ushort2*)(Xb + (size_t)sj * 128))[lane];
        ax += nj * b2f(r.x);
        ay += nj * b2f(r.y);
    }

    if (BIAS_RELU) {
        float2 bv = ((const float2*)bias)[lane];
        ax = fmaxf(ax + bv.x, 0.0f);
        ay = fmaxf(ay + bv.y, 0.0f);
    }
    ushort2 o; o.x = f2b(ax); o.y = f2b(ay);
    ((ushort2*)(outb + (size_t)node * 128))[lane] = o;
}

// C[M,N] = A[M,K] @ Bt[N,K]^T (bf16, row-major), fp32 accum.
// Wave tile 64x64 (4x4 MFMA 16x16x32). kb_per: k-blocks per z-slice (split-K);
// fp32 split-K output goes to C + z*M*N.
template <int WR, int WC, bool HAS_BIAS, bool RELU, bool OUT_BF16>
__global__ __launch_bounds__(WR * WC * 64) void gemm_bt(
    const unsigned short* __restrict__ A, const unsigned short* __restrict__ Bt,
    const float* __restrict__ bias, void* __restrict__ C, int M, int N, int K, int kb_per) {
    constexpr int BM = WR * 64, BN = WC * 64, NT = WR * WC * 64;
    __shared__ __align__(16) unsigned short As[BM * 32];
    __shared__ __align__(16) unsigned short Bs[BN * 32];
    const int tid = threadIdx.x;
    const int wave = tid >> 6, lane = tid & 63;
    const int wr = wave / WC, wc = wave % WC;
    const int lm = lane & 15, quad = lane >> 4;
    const int bm0 = blockIdx.y * BM, bn0 = blockIdx.x * BN;

    f32x4 acc[4][4] = {};

    const int nkb = K >> 5;
    const int kb0 = blockIdx.z * kb_per;
    const int kb1 = min(kb0 + kb_per, nkb);
    for (int kb = kb0; kb < kb1; ++kb) {
        #pragma unroll
        for (int c = tid; c < BM * 4; c += NT) {
            int r = c >> 2, cc = c & 3;
            int gm = bm0 + r;
            int4 v = make_int4(0, 0, 0, 0);
            if (gm < M) v = *(const int4*)(A + (size_t)gm * K + kb * 32 + cc * 8);
            *(int4*)&As[r * 32 + cc * 8] = v;
        }
        #pragma unroll
        for (int c = tid; c < BN * 4; c += NT) {
            int r = c >> 2, cc = c & 3;
            int gn = bn0 + r;
            *(int4*)&Bs[r * 32 + cc * 8] =
                *(const int4*)(Bt + (size_t)gn * K + kb * 32 + cc * 8);
        }
        __syncthreads();
        bf16x8 af[4], bfr[4];
        #pragma unroll
        for (int i = 0; i < 4; i++)
            af[i] = *(const bf16x8*)&As[(wr * 64 + i * 16 + lm) * 32 + quad * 8];
        #pragma unroll
        for (int j = 0; j < 4; j++)
            bfr[j] = *(const bf16x8*)&Bs[(wc * 64 + j * 16 + lm) * 32 + quad * 8];
        #pragma unroll
        for (int i = 0; i < 4; i++)
            #pragma unroll
            for (int j = 0; j < 4; j++)
                acc[i][j] = __builtin_amdgcn_mfma_f32_16x16x32_bf16(af[i], bfr[j], acc[i][j], 0, 0, 0);
        __syncthreads();
    }

    float* Cf = (float*)C + (size_t)blockIdx.z * M * N;
    #pragma unroll
    for (int i = 0; i < 4; i++) {
        int mbase = bm0 + wr * 64 + i * 16 + quad * 4;
        #pragma unroll
        for (int j = 0; j < 4; j++) {
            int col = bn0 + wc * 64 + j * 16 + lm;
            float bv = HAS_BIAS ? bias[col] : 0.0f;
            f32x4 v = acc[i][j];
            #pragma unroll
            for (int r = 0; r < 4; r++) {
                int m = mbase + r;
                if (m < M) {
                    float o = v[r] + bv;
                    if (RELU) o = fmaxf(o, 0.0f);
                    if (OUT_BF16)
                        ((unsigned short*)C)[(size_t)m * N + col] = f2b(o);
                    else
                        Cf[(size_t)m * N + col] = o;
                }
            }
        }
    }
}

// out = relu(part0 + part1 + bias), N=64 cols, float4 per thread
__global__ void k_reduce2(const float* __restrict__ part, const float* __restrict__ bias,
                          float* __restrict__ out, int n4) {
    int i = blockIdx.x * 256 + threadIdx.x;
    if (i >= n4) return;
    float4 a = ((const float4*)part)[i];
    float4 b = ((const float4*)part)[i + n4];
    float4 bv = ((const float4*)bias)[i & 15];
    float4 o;
    o.x = fmaxf(a.x + b.x + bv.x, 0.0f);
    o.y = fmaxf(a.y + b.y + bv.y, 0.0f);
    o.z = fmaxf(a.z + b.z + bv.z, 0.0f);
    o.w = fmaxf(a.w + b.w + bv.w, 0.0f);
    ((float4*)out)[i] = o;
}

static inline int cdiv(long a, long b) { return (int)((a + b - 1) / b); }

extern "C" void kernel_launch(void* const* d_in, const int* in_sizes, int n_in,
                              void* d_out, int out_size, void* d_ws, size_t ws_size,
                              hipStream_t stream) {
    const float* x  = (const float*)d_in[0];
    const int*   ei = (const int*)d_in[1];
    const float* ew = (const float*)d_in[2];
    const float* W1 = (const float*)d_in[3];
    const float* b1 = (const float*)d_in[4];
    const float* W2 = (const float*)d_in[5];
    const float* b2 = (const float*)d_in[6];
    const float* W3 = (const float*)d_in[7];
    const float* b3 = (const float*)d_in[8];
    const float* W4 = (const float*)d_in[9];
    const float* b4 = (const float*)d_in[10];
    const int Nn = in_sizes[0] / 128;   // 50000
    const int E  = in_sizes[1] / 2;     // 800000
    const int* src = ei;
    const int* dst = ei + E;

    char* ws = (char*)d_ws;
    size_t off_b = 0;
    auto alloc = [&](size_t bytes) -> void* {
        void* p = ws + off_b;
        off_b += (bytes + 255) & ~(size_t)255;
        return p;
    };
    float*          dinv  = (float*)alloc((size_t)Nn * 4);
    int*            cnt   = (int*)alloc((size_t)Nn * 4);
    int*            s_src = (int*)alloc((size_t)Nn * ELLW * 4);      // 12.8 MB
    float*          s_w   = (float*)alloc((size_t)Nn * ELLW * 4);    // 12.8 MB (w -> nrm)
    unsigned short* W1t   = (unsigned short*)alloc(512 * 128 * 2);
    unsigned short* W2t   = (unsigned short*)alloc(128 * 512 * 2);
    unsigned short* W3t   = (unsigned short*)alloc(1024 * 128 * 2);
    unsigned short* W4t   = (unsigned short*)alloc(64 * 1024 * 2);
    unsigned short* xb    = (unsigned short*)alloc((size_t)Nn * 128 * 2); // bf16(x); part slab
    unsigned short* t2b   = (unsigned short*)alloc((size_t)Nn * 128 * 2); // bf16 t2; part slab
    unsigned short* actb  = (unsigned short*)alloc((size_t)Nn * 128 * 2); // agg out (bf16)
    unsigned short* h1b   = (unsigned short*)alloc((size_t)Nn * 1024 * 2); // h1(512)/h3(1024)
    unsigned short* h3b   = h1b;
    float*          part  = (float*)xb;   // 2*Nn*64 fp32 overlays xb+t2b (dead by layer 4)
    float*          out   = (float*)d_out;

    // ELL build: zero counts -> 1-atomic fill -> waves compute dinv (no atomics)
    k_zero_int<<<cdiv(Nn, 256), 256, 0, stream>>>(cnt, Nn);
    k_fill_ell<<<cdiv(E, 256), 256, 0, stream>>>(src, dst, ew, cnt, s_src, s_w, E);
    k_deg<<<cdiv(Nn, 4), 256, 0, stream>>>(s_w, cnt, dinv, Nn);

    // weights -> bf16 transposed (one kernel), x -> bf16
    k_wt_all<<<1280, 256, 0, stream>>>(W1, W2, W3, W4, W1t, W2t, W3t, W4t);
    k_f2b4<<<cdiv((size_t)Nn * 32, 256), 256, 0, stream>>>(x, xb, Nn * 32);

    // layer 1: aggregate x_bf16 (computes+stores nrm), GEMM 128->512 +bias+relu
    k_gather<true, false><<<cdiv(Nn, 4), 256, 0, stream>>>(
        xb, s_src, s_w, cnt, dinv, nullptr, actb, Nn);
    gemm_bt<2, 2, true, true, true><<<dim3(4, cdiv(Nn, 128)), 256, 0, stream>>>(
        actb, W1t, b1, h1b, Nn, 512, 128, 4);

    // layer 2: t2 = h1 @ W2 (bf16 out), aggregate +bias+relu
    gemm_bt<1, 2, false, false, true><<<dim3(1, cdiv(Nn, 64)), 128, 0, stream>>>(
        h1b, W2t, nullptr, t2b, Nn, 128, 512, 16);
    k_gather<false, true><<<cdiv(Nn, 4), 256, 0, stream>>>(
        t2b, s_src, s_w, cnt, dinv, b2, actb, Nn);

    // layer 3: h3 = relu(h2 @ W3 + b3)
    gemm_bt<2, 2, true, true, true><<<dim3(8, cdiv(Nn, 128)), 256, 0, stream>>>(
        actb, W3t, b3, h3b, Nn, 1024, 128, 4);

    // layer 4: split-K=2 partials (fp32), then reduce+bias+relu
    gemm_bt<2, 1, false, false, false><<<dim3(1, cdiv(Nn, 128), 2), 128, 0, stream>>>(
        h3b, W4t, nullptr, part, Nn, 64, 1024, 16);
    k_reduce2<<<cdiv(Nn * 16, 256), 256, 0, stream>>>(part, b4, out, Nn * 16);
}

// Round 5
// 351.235 us; speedup vs baseline: 8.6630x; 1.1313x over previous
//
#include <hip/hip_runtime.h>

// MultiLayerGCN on MI355X — round 5: fused layer3+4 MLP kernel (h3 never hits
// HBM), XOR-swizzled LDS, padded gemm_bt staging (no bank conflicts).
// Math: h1 = relu((Anorm@x) @ W1 + b1)
//       t2 = h1 @ W2 (bf16);  h2 = relu(Anorm@t2 + b2)
//       out = relu(relu(h2 @ W3 + b3) @ W4 + b4)     [fused, h3 in LDS only]
// Anorm@y [d] = sum_{e: dst=d} nrm[e]*y[src(e)] + y[d]*dinv[d]^2
// ELL: 64 slots/node (deg ~ Poisson(16); guarded).

#define ELLW 64

typedef short bf16x8 __attribute__((ext_vector_type(8)));
typedef float f32x4 __attribute__((ext_vector_type(4)));

__device__ __forceinline__ unsigned short f2b(float f) {
    unsigned u = __builtin_bit_cast(unsigned, f);
    unsigned r = (u + 0x7FFFu + ((u >> 16) & 1u)) >> 16;
    return (unsigned short)r;
}
__device__ __forceinline__ float b2f(unsigned short u) {
    return __builtin_bit_cast(float, (unsigned)u << 16);
}

__global__ void k_zero_int(int* p, int n) {
    int i = blockIdx.x * 256 + threadIdx.x;
    if (i < n) p[i] = 0;
}

// one atomic per edge: claim slot in dst's ELL row, write (src, w) SoA
__global__ void k_fill_ell(const int* __restrict__ src, const int* __restrict__ dst,
                           const float* __restrict__ w, int* __restrict__ cnt,
                           int* __restrict__ s_src, float* __restrict__ s_w, int E) {
    int e = blockIdx.x * 256 + threadIdx.x;
    if (e >= E) return;
    int d = dst[e];
    int slot = atomicAdd(&cnt[d], 1);
    if (slot < ELLW) {
        size_t idx = (size_t)d * ELLW + slot;
        s_src[idx] = src[e];
        s_w[idx] = w[e];
    }
}

// one wave per node: dinv[node] = rsqrt(1 + sum_j w_j)   (no atomics)
__global__ __launch_bounds__(256) void k_deg(const float* __restrict__ s_w,
                                             const int* __restrict__ cnt,
                                             float* __restrict__ dinv, int Nn) {
    int node = blockIdx.x * 4 + (threadIdx.x >> 6);
    if (node >= Nn) return;
    int lane = threadIdx.x & 63;
    int c = min(cnt[node], ELLW);
    float s = (lane < c) ? s_w[(size_t)node * ELLW + lane] : 0.0f;
    #pragma unroll
    for (int d = 32; d > 0; d >>= 1) s += __shfl_down(s, d);
    if (lane == 0) dinv[node] = rsqrtf(1.0f + s);
}

// fp32 -> bf16, 4 elems/thread
__global__ void k_f2b4(const float* __restrict__ in, unsigned short* __restrict__ out, int n4) {
    int i = blockIdx.x * 256 + threadIdx.x;
    if (i >= n4) return;
    float4 v = ((const float4*)in)[i];
    ushort4 o;
    o.x = f2b(v.x); o.y = f2b(v.y); o.z = f2b(v.z); o.w = f2b(v.w);
    ((ushort4*)out)[i] = o;
}

// all 4 weight transposes fp32[K,N] -> bf16[N,K] in one kernel
__global__ void k_wt_all(const float* __restrict__ W1, const float* __restrict__ W2,
                         const float* __restrict__ W3, const float* __restrict__ W4,
                         unsigned short* __restrict__ W1t, unsigned short* __restrict__ W2t,
                         unsigned short* __restrict__ W3t, unsigned short* __restrict__ W4t) {
    int i = blockIdx.x * 256 + threadIdx.x;
    if (i < 65536) {                       // W1: 128x512
        int k = i >> 9, n = i & 511;
        W1t[n * 128 + k] = f2b(W1[i]);
    } else if (i < 131072) {               // W2: 512x128
        int j = i - 65536; int k = j >> 7, n = j & 127;
        W2t[n * 512 + k] = f2b(W2[j]);
    } else if (i < 262144) {               // W3: 128x1024
        int j = i - 131072; int k = j >> 10, n = j & 1023;
        W3t[n * 128 + k] = f2b(W3[j]);
    } else {                               // W4: 1024x64
        int j = i - 262144; int k = j >> 6, n = j & 63;
        W4t[n * 1024 + k] = f2b(W4[j]);
    }
}

// one wave per node; lane j<c holds edge j's (src, nrm) in regs, broadcast via shfl.
// FIRST: compute nrm = dinv[src]*w*dinv[node], write back for pass 2.
template <bool FIRST, bool BIAS_RELU>
__global__ __launch_bounds__(256) void k_gather(
    const unsigned short* __restrict__ Xb, const int* __restrict__ s_src,
    float* __restrict__ s_w, const int* __restrict__ cnt,
    const float* __restrict__ dinv, const float* __restrict__ bias,
    unsigned short* __restrict__ outb, int Nn) {
    int node = blockIdx.x * 4 + (threadIdx.x >> 6);
    if (node >= Nn) return;
    int lane = threadIdx.x & 63;
    float di = dinv[node];
    float dii = di * di;
    ushort2 sv = ((const ushort2*)(Xb + (size_t)node * 128))[lane];
    float ax = b2f(sv.x) * dii, ay = b2f(sv.y) * dii;

    int c = min(cnt[node], ELLW);
    size_t base = (size_t)node * ELLW;
    int sreg = 0;
    float nv = 0.0f;
    if (lane < c) {
        sreg = s_src[base + lane];
        float wv = s_w[base + lane];
        if (FIRST) {
            nv = dinv[sreg] * wv * di;
            s_w[base + lane] = nv;
        } else {
            nv = wv;
        }
    }

    int j = 0;
    for (; j + 4 <= c; j += 4) {
        int s0 = __shfl(sreg, j),     s1 = __shfl(sreg, j + 1);
        int s2 = __shfl(sreg, j + 2), s3 = __shfl(sreg, j + 3);
        float n0 = __shfl(nv, j),     n1 = __shfl(nv, j + 1);
        float n2 = __shfl(nv, j + 2), n3 = __shfl(nv, j + 3);
        ushort2 r0 = ((const ushort2*)(Xb + (size_t)s0 * 128))[lane];
        ushort2 r1 = ((const ushort2*)(Xb + (size_t)s1 * 128))[lane];
        ushort2 r2 = ((const ushort2*)(Xb + (size_t)s2 * 128))[lane];
        ushort2 r3 = ((const ushort2*)(Xb + (size_t)s3 * 128))[lane];
        ax += n0 * b2f(r0.x) + n1 * b2f(r1.x) + n2 * b2f(r2.x) + n3 * b2f(r3.x);
        ay += n0 * b2f(r0.y) + n1 * b2f(r1.y) + n2 * b2f(r2.y) + n3 * b2f(r3.y);
    }
    for (; j < c; ++j) {
        int sj = __shfl(sreg, j);
        float nj = __shfl(nv, j);
        ushort2 r = ((const ushort2*)(Xb + (size_t)sj * 128))[lane];
        ax += nj * b2f(r.x);
        ay += nj * b2f(r.y);
    }

    if (BIAS_RELU) {
        float2 bv = ((const float2*)bias)[lane];
        ax = fmaxf(ax + bv.x, 0.0f);
        ay = fmaxf(ay + bv.y, 0.0f);
    }
    ushort2 o; o.x = f2b(ax); o.y = f2b(ay);
    ((ushort2*)(outb + (size_t)node * 128))[lane] = o;
}

// C[M,N] = A[M,K] @ Bt[N,K]^T (bf16, row-major), fp32 accum.
// Wave tile 64x64 (4x4 MFMA 16x16x32). LDS row stride 40 shorts (80B: 16B-
// aligned, 20-bank walk -> 2-way max, conflict-free).
template <int WR, int WC, bool HAS_BIAS, bool RELU>
__global__ __launch_bounds__(WR * WC * 64) void gemm_bt(
    const unsigned short* __restrict__ A, const unsigned short* __restrict__ Bt,
    const float* __restrict__ bias, unsigned short* __restrict__ C,
    int M, int N, int K) {
    constexpr int BM = WR * 64, BN = WC * 64, NT = WR * WC * 64;
    __shared__ __align__(16) unsigned short As[BM * 40];
    __shared__ __align__(16) unsigned short Bs[BN * 40];
    const int tid = threadIdx.x;
    const int wave = tid >> 6, lane = tid & 63;
    const int wr = wave / WC, wc = wave % WC;
    const int lm = lane & 15, quad = lane >> 4;
    const int bm0 = blockIdx.y * BM, bn0 = blockIdx.x * BN;

    f32x4 acc[4][4] = {};

    const int nkb = K >> 5;
    for (int kb = 0; kb < nkb; ++kb) {
        #pragma unroll
        for (int c = tid; c < BM * 4; c += NT) {
            int r = c >> 2, cc = c & 3;
            int gm = bm0 + r;
            int4 v = make_int4(0, 0, 0, 0);
            if (gm < M) v = *(const int4*)(A + (size_t)gm * K + kb * 32 + cc * 8);
            *(int4*)&As[r * 40 + cc * 8] = v;
        }
        #pragma unroll
        for (int c = tid; c < BN * 4; c += NT) {
            int r = c >> 2, cc = c & 3;
            int gn = bn0 + r;
            *(int4*)&Bs[r * 40 + cc * 8] =
                *(const int4*)(Bt + (size_t)gn * K + kb * 32 + cc * 8);
        }
        __syncthreads();
        bf16x8 af[4], bfr[4];
        #pragma unroll
        for (int i = 0; i < 4; i++)
            af[i] = *(const bf16x8*)&As[(wr * 64 + i * 16 + lm) * 40 + quad * 8];
        #pragma unroll
        for (int j = 0; j < 4; j++)
            bfr[j] = *(const bf16x8*)&Bs[(wc * 64 + j * 16 + lm) * 40 + quad * 8];
        #pragma unroll
        for (int i = 0; i < 4; i++)
            #pragma unroll
            for (int j = 0; j < 4; j++)
                acc[i][j] = __builtin_amdgcn_mfma_f32_16x16x32_bf16(af[i], bfr[j], acc[i][j], 0, 0, 0);
        __syncthreads();
    }

    #pragma unroll
    for (int i = 0; i < 4; i++) {
        int mbase = bm0 + wr * 64 + i * 16 + quad * 4;
        #pragma unroll
        for (int j = 0; j < 4; j++) {
            int col = bn0 + wc * 64 + j * 16 + lm;
            float bv = HAS_BIAS ? bias[col] : 0.0f;
            f32x4 v = acc[i][j];
            #pragma unroll
            for (int r = 0; r < 4; r++) {
                int m = mbase + r;
                if (m < M) {
                    float o = v[r] + bv;
                    if (RELU) o = fmaxf(o, 0.0f);
                    C[(size_t)m * N + col] = f2b(o);
                }
            }
        }
    }
}

// Fused layers 3+4: out = relu(relu(A@W3+b3)@W4+b4). A: [M][128] bf16.
// W3t: [1024][128] bf16, W4t: [64][1024] bf16. Per block: 128 rows.
// 16 chunks of 64 h3-cols; h3 chunk lives in regs -> wave-private LDS P ->
// second MFMA. XOR-swizzled LDS (8-short groups): 2-way max conflicts.
__global__ __launch_bounds__(256) void k_mlp34(
    const unsigned short* __restrict__ A, const unsigned short* __restrict__ W3t,
    const unsigned short* __restrict__ W4t, const float* __restrict__ b3,
    const float* __restrict__ b4, float* __restrict__ out, int M) {
    __shared__ __align__(16) unsigned short Ash[128 * 128];   // 32 KB
    __shared__ __align__(16) unsigned short BPsh[128 * 64];   // 16 KB: W3 chunk / P overlay
    __shared__ __align__(16) unsigned short W4sh[64 * 64];    // 8 KB
    const int tid = threadIdx.x, wave = tid >> 6, lane = tid & 63;
    const int lm = lane & 15, quad = lane >> 4;
    const int bm0 = blockIdx.x * 128;

    // stage A tile: 128 rows x 16 groups of 8 shorts, swizzled g^(r&15)
    for (int u = tid; u < 2048; u += 256) {
        int r = u >> 4, g = u & 15;
        int gm = bm0 + r;
        int4 v = make_int4(0, 0, 0, 0);
        if (gm < M) v = *(const int4*)(A + (size_t)gm * 128 + g * 8);
        *(int4*)&Ash[r * 128 + ((g ^ (r & 15)) * 8)] = v;
    }

    f32x4 oacc[2][4] = {};
    for (int c = 0; c < 16; ++c) {
        // stage W3 chunk (rows c*64..+64 of W3t, 128 K each) into BPsh
        for (int u = tid; u < 1024; u += 256) {
            int r = u >> 4, g = u & 15;
            *(int4*)&BPsh[r * 128 + ((g ^ (r & 15)) * 8)] =
                *(const int4*)(W3t + (size_t)(c * 64 + r) * 128 + g * 8);
        }
        // stage W4 chunk (64 rows x k = c*64..+64), swizzled g^(r&7)
        for (int u = tid; u < 512; u += 256) {
            int r = u >> 3, g = u & 7;
            *(int4*)&W4sh[r * 64 + ((g ^ (r & 7)) * 8)] =
                *(const int4*)(W4t + (size_t)r * 1024 + c * 64 + g * 8);
        }
        __syncthreads();

        // GEMM-3 chunk: wave computes h3 rows [wave*32, +32) x 64 cols
        f32x4 hacc[2][4] = {};
        #pragma unroll
        for (int kb = 0; kb < 4; ++kb) {
            bf16x8 af[2], bfr[4];
            #pragma unroll
            for (int i = 0; i < 2; ++i) {
                int r = wave * 32 + i * 16 + lm;
                int g = kb * 4 + quad;
                af[i] = *(const bf16x8*)&Ash[r * 128 + ((g ^ (r & 15)) * 8)];
            }
            #pragma unroll
            for (int j = 0; j < 4; ++j) {
                int r = j * 16 + lm;
                int g = kb * 4 + quad;
                bfr[j] = *(const bf16x8*)&BPsh[r * 128 + ((g ^ (r & 15)) * 8)];
            }
            #pragma unroll
            for (int i = 0; i < 2; ++i)
                #pragma unroll
                for (int j = 0; j < 4; ++j)
                    hacc[i][j] = __builtin_amdgcn_mfma_f32_16x16x32_bf16(
                        af[i], bfr[j], hacc[i][j], 0, 0, 0);
        }
        __syncthreads();   // all waves done reading W3 chunk before P overwrite

        // epilogue -> P (wave-private rows): bias+relu+bf16, swizzled rows of 64
        #pragma unroll
        for (int i = 0; i < 2; ++i) {
            #pragma unroll
            for (int j = 0; j < 4; ++j) {
                int col = j * 16 + lm;
                float bv = b3[c * 64 + col];
                #pragma unroll
                for (int r4 = 0; r4 < 4; ++r4) {
                    int row = wave * 32 + i * 16 + quad * 4 + r4;
                    float o = fmaxf(hacc[i][j][r4] + bv, 0.0f);
                    int g = col >> 3;
                    BPsh[row * 64 + ((g ^ (row & 7)) * 8) + (col & 7)] = f2b(o);
                }
            }
        }

        // GEMM-4 chunk: out rows [wave*32,+32) x 64 cols, K-chunk 64
        #pragma unroll
        for (int kb = 0; kb < 2; ++kb) {
            bf16x8 pf[2], wf[4];
            #pragma unroll
            for (int i = 0; i < 2; ++i) {
                int r = wave * 32 + i * 16 + lm;
                int g = kb * 4 + quad;
                pf[i] = *(const bf16x8*)&BPsh[r * 64 + ((g ^ (r & 7)) * 8)];
            }
            #pragma unroll
            for (int j = 0; j < 4; ++j) {
                int r = j * 16 + lm;
                int g = kb * 4 + quad;
                wf[j] = *(const bf16x8*)&W4sh[r * 64 + ((g ^ (r & 7)) * 8)];
            }
            #pragma unroll
            for (int i = 0; i < 2; ++i)
                #pragma unroll
                for (int j = 0; j < 4; ++j)
                    oacc[i][j] = __builtin_amdgcn_mfma_f32_16x16x32_bf16(
                        pf[i], wf[j], oacc[i][j], 0, 0, 0);
        }
        __syncthreads();   // before restaging next chunk
    }

    // final epilogue: +b4, relu, fp32 store
    #pragma unroll
    for (int i = 0; i < 2; ++i) {
        #pragma unroll
        for (int j = 0; j < 4; ++j) {
            int col = j * 16 + lm;
            float bv = b4[col];
            #pragma unroll
            for (int r4 = 0; r4 < 4; ++r4) {
                int m = bm0 + wave * 32 + i * 16 + quad * 4 + r4;
                if (m < M)
                    out[(size_t)m * 64 + col] = fmaxf(oacc[i][j][r4] + bv, 0.0f);
            }
        }
    }
}

static inline int cdiv(long a, long b) { return (int)((a + b - 1) / b); }

extern "C" void kernel_launch(void* const* d_in, const int* in_sizes, int n_in,
                              void* d_out, int out_size, void* d_ws, size_t ws_size,
                              hipStream_t stream) {
    const float* x  = (const float*)d_in[0];
    const int*   ei = (const int*)d_in[1];
    const float* ew = (const float*)d_in[2];
    const float* W1 = (const float*)d_in[3];
    const float* b1 = (const float*)d_in[4];
    const float* W2 = (const float*)d_in[5];
    const float* b2 = (const float*)d_in[6];
    const float* W3 = (const float*)d_in[7];
    const float* b3 = (const float*)d_in[8];
    const float* W4 = (const float*)d_in[9];
    const float* b4 = (const float*)d_in[10];
    const int Nn = in_sizes[0] / 128;   // 50000
    const int E  = in_sizes[1] / 2;     // 800000
    const int* src = ei;
    const int* dst = ei + E;

    char* ws = (char*)d_ws;
    size_t off_b = 0;
    auto alloc = [&](size_t bytes) -> void* {
        void* p = ws + off_b;
        off_b += (bytes + 255) & ~(size_t)255;
        return p;
    };
    float*          dinv  = (float*)alloc((size_t)Nn * 4);
    int*            cnt   = (int*)alloc((size_t)Nn * 4);
    int*            s_src = (int*)alloc((size_t)Nn * ELLW * 4);
    float*          s_w   = (float*)alloc((size_t)Nn * ELLW * 4);    // w -> nrm
    unsigned short* W1t   = (unsigned short*)alloc(512 * 128 * 2);
    unsigned short* W2t   = (unsigned short*)alloc(128 * 512 * 2);
    unsigned short* W3t   = (unsigned short*)alloc(1024 * 128 * 2);
    unsigned short* W4t   = (unsigned short*)alloc(64 * 1024 * 2);
    unsigned short* xb    = (unsigned short*)alloc((size_t)Nn * 128 * 2);
    unsigned short* t2b   = (unsigned short*)alloc((size_t)Nn * 128 * 2);
    unsigned short* actb  = (unsigned short*)alloc((size_t)Nn * 128 * 2);
    unsigned short* h1b   = (unsigned short*)alloc((size_t)Nn * 512 * 2);
    float*          out   = (float*)d_out;

    // ELL build
    k_zero_int<<<cdiv(Nn, 256), 256, 0, stream>>>(cnt, Nn);
    k_fill_ell<<<cdiv(E, 256), 256, 0, stream>>>(src, dst, ew, cnt, s_src, s_w, E);
    k_deg<<<cdiv(Nn, 4), 256, 0, stream>>>(s_w, cnt, dinv, Nn);

    // weight + input conversion
    k_wt_all<<<1280, 256, 0, stream>>>(W1, W2, W3, W4, W1t, W2t, W3t, W4t);
    k_f2b4<<<cdiv((size_t)Nn * 32, 256), 256, 0, stream>>>(x, xb, Nn * 32);

    // layer 1: aggregate x (computes+stores nrm), GEMM 128->512 +bias+relu
    k_gather<true, false><<<cdiv(Nn, 4), 256, 0, stream>>>(
        xb, s_src, s_w, cnt, dinv, nullptr, actb, Nn);
    gemm_bt<2, 2, true, true><<<dim3(4, cdiv(Nn, 128)), 256, 0, stream>>>(
        actb, W1t, b1, h1b, Nn, 512, 128);

    // layer 2: t2 = h1 @ W2 (bf16), aggregate +bias+relu
    gemm_bt<1, 2, false, false><<<dim3(1, cdiv(Nn, 64)), 128, 0, stream>>>(
        h1b, W2t, nullptr, t2b, Nn, 128, 512);
    k_gather<false, true><<<cdiv(Nn, 4), 256, 0, stream>>>(
        t2b, s_src, s_w, cnt, dinv, b2, actb, Nn);

    // layers 3+4 fused
    k_mlp34<<<cdiv(Nn, 128), 256, 0, stream>>>(actb, W3t, W4t, b3, b4, out, Nn);
}